// Round 10
// baseline (924.791 us; speedup 1.0000x reference)
//
#include <hip/hip_runtime.h>
#include <math.h>

#define NB   16      // batch
#define SEQL 197     // sequence length (196 patches + cls)
#define TB   (NB*SEQL)   // 3152 tokens
#define DIMM 256
#define DI   512
#define DS   16
#define NL   8

#define SCT 32
#define NCH ((SEQL + SCT - 1)/SCT)   // 7 chunks
#define NDL 8                        // d-channels per scan block
#define NCHAIN (NB*DI*DS)            // 131072 scan chains

typedef __bf16 bf16x8 __attribute__((ext_vector_type(8)));
typedef __bf16 bf16x4 __attribute__((ext_vector_type(4)));
typedef float floatx4 __attribute__((ext_vector_type(4)));

// ---------------- block-wide 2-value reduction (256 threads = 4 waves) -----
__device__ __forceinline__ void block_reduce_2(float& s1, float& s2, float* red, int tid){
  #pragma unroll
  for (int off = 32; off > 0; off >>= 1){
    s1 += __shfl_down(s1, off, 64);
    s2 += __shfl_down(s2, off, 64);
  }
  __syncthreads();
  if ((tid & 63) == 0){ red[(tid>>6)*2] = s1; red[(tid>>6)*2+1] = s2; }
  __syncthreads();
  s1 = red[0] + red[2] + red[4] + red[6];
  s2 = red[1] + red[3] + red[5] + red[7];
}

// ---------------- weight cast+transpose: in[K][N] fp32 -> out[N][K] bf16 ---
__global__ __launch_bounds__(256) void transpose_bf16(
    const float* __restrict__ in, __bf16* __restrict__ out, int K, int N)
{
  __shared__ float t[32][33];
  const float* src = in  + (size_t)blockIdx.z*K*N;
  __bf16*      dst = out + (size_t)blockIdx.z*K*N;
  int n0 = blockIdx.x*32, k0 = blockIdx.y*32;
  int tx = threadIdx.x & 31, ty = threadIdx.x >> 5;   // 32 x 8
  #pragma unroll
  for (int j = 0; j < 4; j++)
    t[ty + j*8][tx] = src[(size_t)(k0 + ty + j*8)*N + n0 + tx];
  __syncthreads();
  #pragma unroll
  for (int j = 0; j < 4; j++)
    dst[(size_t)(n0 + ty + j*8)*K + k0 + tx] = (__bf16)t[tx][ty + j*8];
}

// in[K][Nin] fp32 -> out[Npad][K] bf16, rows >= Nin zeroed
__global__ __launch_bounds__(256) void transpose_bf16_pad(
    const float* __restrict__ in, __bf16* __restrict__ out, int K, int Nin, int Npad)
{
  __shared__ float t[32][33];
  const float* src = in  + (size_t)blockIdx.z*K*Nin;
  __bf16*      dst = out + (size_t)blockIdx.z*Npad*K;
  int n0 = blockIdx.x*32, k0 = blockIdx.y*32;
  int tx = threadIdx.x & 31, ty = threadIdx.x >> 5;
  #pragma unroll
  for (int j = 0; j < 4; j++){
    int n = n0 + tx;
    t[ty + j*8][tx] = (n < Nin) ? src[(size_t)(k0 + ty + j*8)*Nin + n] : 0.f;
  }
  __syncthreads();
  #pragma unroll
  for (int j = 0; j < 4; j++)
    dst[(size_t)(n0 + ty + j*8)*K + k0 + tx] = (__bf16)t[tx][ty + j*8];
}

// ---------------- bf16 MFMA GEMM: C fp32 = A[M][K] @ Wt[N][K]^T (+bias) ----
// Known-good BK=32 inner loop (R5/R7). Only tile/grid shapes tuned.
template<int BM, int BN>
__global__ __launch_bounds__(256) void gemm_bf16(
    const __bf16* __restrict__ A, const __bf16* __restrict__ Wt,
    const float* __restrict__ bias, float* __restrict__ C, int M, int N, int K)
{
  constexpr int BK  = 32;
  constexpr int LDA = BK + 8;
  constexpr int TMW = BM/32;
  constexpr int TNW = BN/32;
  __shared__ __bf16 As[BM][LDA];
  __shared__ __bf16 Bs[BN][LDA];

  int tid  = threadIdx.x;
  int lane = tid & 63, w = tid >> 6;
  int wm = w >> 1, wn = w & 1;
  int l15 = lane & 15, quad = lane >> 4;
  int bm = blockIdx.y * BM, bn = blockIdx.x * BN;

  floatx4 acc[TMW][TNW] = {};

  for (int k0 = 0; k0 < K; k0 += BK){
    #pragma unroll
    for (int i = 0; i < BM/64; i++){
      int c = tid + i*256;
      int row = c >> 2, kc = c & 3;
      int m = bm + row;
      uint4 v = make_uint4(0,0,0,0);
      if (m < M) v = ((const uint4*)(A + (size_t)m*K + k0))[kc];
      *(uint4*)&As[row][kc*8] = v;
    }
    #pragma unroll
    for (int i = 0; i < BN/64; i++){
      int c = tid + i*256;
      int row = c >> 2, kc = c & 3;
      int n = bn + row;
      uint4 v = ((const uint4*)(Wt + (size_t)n*K + k0))[kc];
      *(uint4*)&Bs[row][kc*8] = v;
    }
    __syncthreads();
    bf16x8 af[TMW], bf[TNW];
    #pragma unroll
    for (int mi = 0; mi < TMW; mi++)
      af[mi] = *(const bf16x8*)&As[wm*(BM/2) + mi*16 + l15][quad*8];
    #pragma unroll
    for (int ni = 0; ni < TNW; ni++)
      bf[ni] = *(const bf16x8*)&Bs[wn*(BN/2) + ni*16 + l15][quad*8];
    #pragma unroll
    for (int mi = 0; mi < TMW; mi++)
      #pragma unroll
      for (int ni = 0; ni < TNW; ni++)
        acc[mi][ni] = __builtin_amdgcn_mfma_f32_16x16x32_bf16(af[mi], bf[ni], acc[mi][ni], 0, 0, 0);
    __syncthreads();
  }
  #pragma unroll
  for (int mi = 0; mi < TMW; mi++){
    #pragma unroll
    for (int ni = 0; ni < TNW; ni++){
      int col = bn + wn*(BN/2) + ni*16 + l15;
      float bv = bias ? bias[col] : 0.f;
      #pragma unroll
      for (int r = 0; r < 4; r++){
        int row = bm + wm*(BM/2) + mi*16 + quad*4 + r;
        if (row < M) C[(size_t)row*N + col] = acc[mi][ni][r] + bv;
      }
    }
  }
}

// ---------------- patch LN1: gather + LayerNorm(768) -> bf16 ---------------
__global__ __launch_bounds__(256) void patch_ln1(
    const float* __restrict__ img, const float* __restrict__ g1, const float* __restrict__ b1,
    __bf16* __restrict__ xp_bf)
{
  __shared__ float red[8];
  int blk = blockIdx.x;            // b*196 + patch
  int b = blk / 196, p = blk % 196;
  int hh = p / 14, ww = p % 14;
  int tid = threadIdx.x;

  float v[3]; float s = 0.f, s2 = 0.f;
  #pragma unroll
  for (int i = 0; i < 3; i++){
    int e  = tid + i*256;
    int c  = e % 3;
    int p2 = (e/3) % 16;
    int p1 = e / 48;
    float val = img[((b*3 + c)*224 + hh*16 + p1)*224 + ww*16 + p2];
    v[i] = val; s += val; s2 += val*val;
  }
  block_reduce_2(s, s2, red, tid);
  float mu = s * (1.f/768.f);
  float var = s2 * (1.f/768.f) - mu*mu;
  float rr = rsqrtf(var + 1e-5f);
  #pragma unroll
  for (int i = 0; i < 3; i++){
    int e = tid + i*256;
    xp_bf[(size_t)blk*768 + e] = (__bf16)((v[i] - mu) * rr * g1[e] + b1[e]);
  }
}

// ---------------- patch LN2 + pos, and cls+pos (fused, grid NB*SEQL) -------
__global__ __launch_bounds__(256) void ln2_cls_pos(
    const float* __restrict__ pemb, const float* __restrict__ g2, const float* __restrict__ b2,
    const float* __restrict__ pos, const float* __restrict__ cls, float* __restrict__ x)
{
  __shared__ float red[8];
  int blk = blockIdx.x;            // b*197 + l
  int b = blk / SEQL, l = blk % SEQL;
  int tid = threadIdx.x;
  if (l == 0){
    x[(size_t)b*SEQL*256 + tid] = cls[tid] + pos[tid];
    return;
  }
  int p = l - 1;
  float v = pemb[(size_t)(b*196 + p)*256 + tid];
  float s = v, s2 = v*v;
  block_reduce_2(s, s2, red, tid);
  float mu = s * (1.f/256.f);
  float var = s2 * (1.f/256.f) - mu*mu;
  float rr = rsqrtf(var + 1e-5f);
  float o = (v - mu) * rr * g2[tid] + b2[tid] + pos[(1+p)*256 + tid];
  x[((size_t)(b*SEQL + 1 + p))*256 + tid] = o;
}

// ---------------- residual add + LayerNorm(256) -> bf16, wave-per-token ----
__global__ __launch_bounds__(256) void add_ln(
    const float* __restrict__ x, float* __restrict__ resid, __bf16* __restrict__ xn_bf,
    const float* __restrict__ g, const float* __restrict__ bta, int first)
{
  int w = threadIdx.x >> 6, l = threadIdx.x & 63;
  int t = blockIdx.x*4 + w;
  size_t base = (size_t)t*256 + l*4;
  float4 xv = *(const float4*)&x[base];
  if (!first){
    float4 rv = *(const float4*)&resid[base];
    xv.x += rv.x; xv.y += rv.y; xv.z += rv.z; xv.w += rv.w;
  }
  *(float4*)&resid[base] = xv;
  float s  = xv.x + xv.y + xv.z + xv.w;
  float s2 = xv.x*xv.x + xv.y*xv.y + xv.z*xv.z + xv.w*xv.w;
  #pragma unroll
  for (int off = 1; off < 64; off <<= 1){
    s  += __shfl_xor(s,  off, 64);
    s2 += __shfl_xor(s2, off, 64);
  }
  float mu = s * (1.f/256.f);
  float var = s2 * (1.f/256.f) - mu*mu;
  float rr = rsqrtf(var + 1e-5f);
  float4 gv = *(const float4*)&g[l*4];
  float4 bv = *(const float4*)&bta[l*4];
  bf16x4 o;
  o[0] = (__bf16)((xv.x - mu)*rr*gv.x + bv.x);
  o[1] = (__bf16)((xv.y - mu)*rr*gv.y + bv.y);
  o[2] = (__bf16)((xv.z - mu)*rr*gv.z + bv.z);
  o[3] = (__bf16)((xv.w - mu)*rr*gv.w + bv.w);
  *(bf16x4*)&xn_bf[base] = o;
}

// ---------------- causal depthwise conv (k=4) + SiLU, float4 ---------------
__global__ __launch_bounds__(256) void conv_silu(
    const float* __restrict__ xz, const float* __restrict__ cw, const float* __restrict__ cb,
    float* __restrict__ u, __bf16* __restrict__ u_bf)
{
  int gid = blockIdx.x*256 + threadIdx.x;   // t*128 + dq
  int dq = gid & 127;
  int t = gid >> 7;
  int d = dq*4;
  int l = t % SEQL;
  const float4 z4 = make_float4(0.f,0.f,0.f,0.f);
  float4 x0 = *(const float4*)&xz[(size_t)t*1024 + d];
  float4 x1 = (l>=1) ? *(const float4*)&xz[(size_t)(t-1)*1024 + d] : z4;
  float4 x2 = (l>=2) ? *(const float4*)&xz[(size_t)(t-2)*1024 + d] : z4;
  float4 x3 = (l>=3) ? *(const float4*)&xz[(size_t)(t-3)*1024 + d] : z4;
  float4 w0 = *(const float4*)&cw[(d+0)*4];
  float4 w1 = *(const float4*)&cw[(d+1)*4];
  float4 w2 = *(const float4*)&cw[(d+2)*4];
  float4 w3 = *(const float4*)&cw[(d+3)*4];
  float4 r = *(const float4*)&cb[d];
  r.x += x3.x*w0.x + x2.x*w0.y + x1.x*w0.z + x0.x*w0.w;
  r.y += x3.y*w1.x + x2.y*w1.y + x1.y*w1.z + x0.y*w1.w;
  r.z += x3.z*w2.x + x2.z*w2.y + x1.z*w2.z + x0.z*w2.w;
  r.w += x3.w*w3.x + x2.w*w3.y + x1.w*w3.z + x0.w*w3.w;
  r.x *= 1.f/(1.f + __expf(-r.x));
  r.y *= 1.f/(1.f + __expf(-r.y));
  r.z *= 1.f/(1.f + __expf(-r.z));
  r.w *= 1.f/(1.f + __expf(-r.w));
  *(float4*)&u[(size_t)t*512 + d] = r;
  bf16x4 o; o[0]=(__bf16)r.x; o[1]=(__bf16)r.y; o[2]=(__bf16)r.z; o[3]=(__bf16)r.w;
  *(bf16x4*)&u_bf[(size_t)t*512 + d] = o;
}

// ============ chunked-parallel selective scan ==============================
// h_t = a_t h_{t-1} + x_t,  a_t = exp(dt_t A),  x_t = dt_t u_t B_t.
// Phase 1: per (chunk, b, d-group): local scan from 0 -> (h_end, P=prod a).
// Phase 2: per chain: serial 7-step carry H_{c+1} = hL_c + P_c H_c.
// Phase 3: per (chunk, b, d-group): recompute local scan, y = C(hL + P*H_c),
//          gate + store. Chain index = b*8192 + dg*128 + tid (coalesced).
// dbc is [TB][64]: cols 0:16 dt_in, 16:32 B, 32:48 C.

__global__ __launch_bounds__(128) void scan_part(
    const float* __restrict__ u, const float* __restrict__ dbc,
    const float* __restrict__ A_log,
    const float* __restrict__ dtw, const float* __restrict__ dtb,
    float* __restrict__ hL_g, float* __restrict__ P_g)
{
  __shared__ float s_D [16][36];
  __shared__ float s_B [16][36];
  __shared__ float s_u [NDL][36];
  __shared__ float s_dt[NDL][36];

  int tid = threadIdx.x;                // dl*16 + n
  int n = tid & 15, dl = tid >> 4;
  int bid = blockIdx.x;
  int c  = bid / (NB*64);               // chunk 0..5 (chunk 6 end-state unused)
  int rem = bid - c*(NB*64);
  int b = rem >> 6, dg = rem & 63;
  int d0 = dg * NDL;
  const size_t base = (size_t)b * SEQL;

  float A = -__expf(A_log[(d0+dl)*DS + n]);
  int cch = tid & 7;
  float wc[16];
  #pragma unroll
  for (int k = 0; k < 16; k++) wc[k] = dtw[k*512 + d0 + cch];
  float dtbv = dtb[d0 + cch];

  #pragma unroll
  for (int i = 0; i < 2; i++){
    int v = tid + i*128;
    int tg = c*SCT + (v>>3); if (tg > SEQL-1) tg = SEQL-1;
    s_u[v&7][v>>3] = u[(base + tg)*512 + d0 + (v&7)];
  }
  #pragma unroll
  for (int s = 0; s < 2; s++)
    #pragma unroll
    for (int i = 0; i < 4; i++){
      int v = tid + i*128;
      int tg = c*SCT + (v>>4); if (tg > SEQL-1) tg = SEQL-1;
      float val = dbc[(base + tg)*64 + s*16 + (v&15)];
      if (s == 0) s_D[v&15][v>>4] = val; else s_B[v&15][v>>4] = val;
    }
  __syncthreads();
  #pragma unroll
  for (int i = 0; i < 2; i++){
    int tl = (tid >> 3) + i*16;
    float acc = dtbv;
    #pragma unroll
    for (int k = 0; k < 16; k++) acc += s_D[k][tl] * wc[k];
    s_dt[cch][tl] = (acc > 20.f) ? acc : log1pf(__expf(acc));
  }
  __syncthreads();

  float h = 0.f, P = 1.f;
  float4 dt4, u4, B4;
  #pragma unroll
  for (int tl = 0; tl < SCT; tl++){
    if ((tl & 3) == 0){
      dt4 = *(const float4*)&s_dt[dl][tl];
      u4  = *(const float4*)&s_u [dl][tl];
      B4  = *(const float4*)&s_B [n][tl];
    }
    float dtv = ((float*)&dt4)[tl&3];
    float uv  = ((float*)&u4 )[tl&3];
    float Bv  = ((float*)&B4 )[tl&3];
    float a = __expf(dtv * A);
    h = a * h + (dtv * uv) * Bv;
    P *= a;
  }
  int chain = b*8192 + d0*16 + tid;
  hL_g[(size_t)c*NCHAIN + chain] = h;
  P_g [(size_t)c*NCHAIN + chain] = P;
}

__global__ __launch_bounds__(256) void scan_carry(
    const float* __restrict__ hL_g, const float* __restrict__ P_g,
    float* __restrict__ Hc_g)
{
  int chain = blockIdx.x*256 + threadIdx.x;
  float H = 0.f;
  #pragma unroll
  for (int c = 0; c < NCH; c++){
    Hc_g[(size_t)c*NCHAIN + chain] = H;
    if (c < NCH-1)
      H = hL_g[(size_t)c*NCHAIN + chain] + P_g[(size_t)c*NCHAIN + chain] * H;
  }
}

__global__ __launch_bounds__(128) void scan_final(
    const float* __restrict__ u, const float* __restrict__ dbc,
    const float* __restrict__ xz, const float* __restrict__ A_log, const float* __restrict__ Dp,
    const float* __restrict__ dtw, const float* __restrict__ dtb,
    const float* __restrict__ Hc_g, __bf16* __restrict__ yg_bf)
{
  __shared__ float s_D [16][36];
  __shared__ float s_B [16][36];
  __shared__ float s_C [16][36];
  __shared__ float s_u [NDL][36];
  __shared__ float s_z [NDL][36];
  __shared__ float s_dt[NDL][36];
  __shared__ float s_yp[SCT][NDL][20];
  __shared__ float s_dp[NDL];

  int tid = threadIdx.x;
  int n = tid & 15, dl = tid >> 4;
  int bid = blockIdx.x;
  int c  = bid / (NB*64);               // chunk 0..6
  int rem = bid - c*(NB*64);
  int b = rem >> 6, dg = rem & 63;
  int d0 = dg * NDL;
  const size_t base = (size_t)b * SEQL;

  float A = -__expf(A_log[(d0+dl)*DS + n]);
  if (tid < NDL) s_dp[tid] = Dp[d0 + tid];
  int cch = tid & 7;
  float wc[16];
  #pragma unroll
  for (int k = 0; k < 16; k++) wc[k] = dtw[k*512 + d0 + cch];
  float dtbv = dtb[d0 + cch];
  int chain = b*8192 + d0*16 + tid;
  float H = Hc_g[(size_t)c*NCHAIN + chain];

  #pragma unroll
  for (int i = 0; i < 2; i++){
    int v = tid + i*128;
    int tg = c*SCT + (v>>3); if (tg > SEQL-1) tg = SEQL-1;
    size_t t = base + tg;
    s_u[v&7][v>>3] = u [t*512 + d0 + (v&7)];
    s_z[v&7][v>>3] = xz[t*1024 + 512 + d0 + (v&7)];
  }
  #pragma unroll
  for (int s = 0; s < 3; s++)
    #pragma unroll
    for (int i = 0; i < 4; i++){
      int v = tid + i*128;
      int tg = c*SCT + (v>>4); if (tg > SEQL-1) tg = SEQL-1;
      float val = dbc[(base + tg)*64 + s*16 + (v&15)];
      if (s == 0)      s_D[v&15][v>>4] = val;
      else if (s == 1) s_B[v&15][v>>4] = val;
      else             s_C[v&15][v>>4] = val;
    }
  __syncthreads();
  #pragma unroll
  for (int i = 0; i < 2; i++){
    int tl = (tid >> 3) + i*16;
    float acc = dtbv;
    #pragma unroll
    for (int k = 0; k < 16; k++) acc += s_D[k][tl] * wc[k];
    s_dt[cch][tl] = (acc > 20.f) ? acc : log1pf(__expf(acc));
  }
  __syncthreads();

  float h = 0.f, P = 1.f;
  float4 dt4, u4, B4, C4;
  #pragma unroll
  for (int tl = 0; tl < SCT; tl++){
    if ((tl & 3) == 0){
      dt4 = *(const float4*)&s_dt[dl][tl];
      u4  = *(const float4*)&s_u [dl][tl];
      B4  = *(const float4*)&s_B [n][tl];
      C4  = *(const float4*)&s_C [n][tl];
    }
    float dtv = ((float*)&dt4)[tl&3];
    float uv  = ((float*)&u4 )[tl&3];
    float Bv  = ((float*)&B4 )[tl&3];
    float Cv  = ((float*)&C4 )[tl&3];
    float a = __expf(dtv * A);
    h = a * h + (dtv * uv) * Bv;
    P *= a;
    s_yp[tl][dl][n] = (h + P*H) * Cv;
  }
  __syncthreads();

  #pragma unroll
  for (int j = 0; j < 2; j++){
    int p = tid + j*128;
    int tl = p >> 3, dr = p & 7;
    float4 a0 = *(const float4*)&s_yp[tl][dr][0];
    float4 a1 = *(const float4*)&s_yp[tl][dr][4];
    float4 a2 = *(const float4*)&s_yp[tl][dr][8];
    float4 a3 = *(const float4*)&s_yp[tl][dr][12];
    float yv = ((a0.x+a0.y)+(a0.z+a0.w)) + ((a1.x+a1.y)+(a1.z+a1.w))
             + ((a2.x+a2.y)+(a2.z+a2.w)) + ((a3.x+a3.y)+(a3.z+a3.w));
    int tg = c*SCT + tl;
    if (tg < SEQL){
      float uv = s_u[dr][tl];
      float zv = s_z[dr][tl];
      float sg = 1.f / (1.f + __expf(-zv));
      yg_bf[(base + tg)*512 + d0 + dr] = (__bf16)((yv + uv*s_dp[dr]) * zv * sg);
    }
  }
}

// ---------------- final LN (token 0) ---------------------------------------
__global__ __launch_bounds__(256) void final_ln(
    const float* __restrict__ x, const float* __restrict__ resid,
    const float* __restrict__ g, const float* __restrict__ bta, float* __restrict__ xs_g)
{
  __shared__ float red[8];
  int b = blockIdx.x, tid = threadIdx.x;
  size_t idx = (size_t)b*SEQL*256 + tid;
  float r = x[idx] + resid[idx];
  float s = r, s2 = r*r;
  block_reduce_2(s, s2, red, tid);
  float mu = s * (1.f/256.f);
  float var = s2 * (1.f/256.f) - mu*mu;
  float rr = rsqrtf(var + 1e-5f);
  xs_g[b*256 + tid] = (r - mu) * rr * g[tid] + bta[tid];
}

// ---------------- head: out[16][1000] = xs[16][256] @ head_w + head_b ------
__global__ __launch_bounds__(256) void head_gemm(
    const float* __restrict__ xs_g, const float* __restrict__ head_w,
    const float* __restrict__ head_b, float* __restrict__ out)
{
  __shared__ float xs[16][256];
  int tid = threadIdx.x;
  #pragma unroll
  for (int i = 0; i < 16; i++) ((float*)xs)[tid + i*256] = xs_g[tid + i*256];
  __syncthreads();
  int nl = tid & 31, bq = tid >> 5;
  int nn = blockIdx.x*32 + nl;
  if (nn >= 1000) return;
  float acc0 = 0.f, acc1 = 0.f;
  #pragma unroll 8
  for (int k = 0; k < 256; k++){
    float w = head_w[k*1000 + nn];
    acc0 += xs[bq][k]   * w;
    acc1 += xs[bq+8][k] * w;
  }
  float hb = head_b[nn];
  out[(size_t)bq*1000 + nn]     = acc0 + hb;
  out[(size_t)(bq+8)*1000 + nn] = acc1 + hb;
}

// ---------------------------------------------------------------------------
extern "C" void kernel_launch(void* const* d_in, const int* in_sizes, int n_in,
                              void* d_out, int out_size, void* d_ws, size_t ws_size,
                              hipStream_t stream) {
  const float* img   = (const float*)d_in[0];
  const float* ln1g  = (const float*)d_in[1];
  const float* ln1b  = (const float*)d_in[2];
  const float* pe_w  = (const float*)d_in[3];
  const float* pe_b  = (const float*)d_in[4];
  const float* ln2g  = (const float*)d_in[5];
  const float* ln2b  = (const float*)d_in[6];
  const float* pos   = (const float*)d_in[7];
  const float* cls   = (const float*)d_in[8];
  const float* ln_w  = (const float*)d_in[9];
  const float* ln_b  = (const float*)d_in[10];
  const float* in_w  = (const float*)d_in[11];
  const float* conv_w= (const float*)d_in[12];
  const float* conv_b= (const float*)d_in[13];
  const float* xproj = (const float*)d_in[14];
  const float* dtw   = (const float*)d_in[15];
  const float* dtb   = (const float*)d_in[16];
  const float* A_log = (const float*)d_in[17];
  const float* Dp    = (const float*)d_in[18];
  const float* out_w = (const float*)d_in[19];
  const float* nfw   = (const float*)d_in[20];
  const float* nfb   = (const float*)d_in[21];
  const float* head_w= (const float*)d_in[22];
  const float* head_b= (const float*)d_in[23];
  float* out = (float*)d_out;

  float* ws = (float*)d_ws;
  float* x     = ws;  ws += (size_t)TB*DIMM;
  float* resid = ws;  ws += (size_t)TB*DIMM;
  float* xz    = ws;  ws += (size_t)TB*2*DI;
  float* u     = ws;  ws += (size_t)TB*DI;
  float* dbc   = ws;  ws += (size_t)TB*64;      // padded N=64 layout
  float* xs_g  = ws;  ws += (size_t)NB*DIMM;
  float* hL_g  = ws;  ws += (size_t)(NCH-1)*NCHAIN;
  float* P_g   = ws;  ws += (size_t)(NCH-1)*NCHAIN;
  float* Hc_g  = ws;  ws += (size_t)NCH*NCHAIN;
  __bf16* xn_bf = (__bf16*)ws;  ws += (size_t)TB*DIMM/2;
  __bf16* u_bf  = (__bf16*)ws;  ws += (size_t)TB*DI/2;
  __bf16* yg_bf = (__bf16*)ws;  ws += (size_t)TB*DI/2;
  __bf16* wt_in = (__bf16*)ws;  ws += (size_t)NL*1024*256/2;
  __bf16* wt_out= (__bf16*)ws;  ws += (size_t)NL*256*512/2;
  __bf16* wt_pe = (__bf16*)ws;  ws += (size_t)256*768/2;
  __bf16* wt_xp = (__bf16*)ws;  ws += (size_t)NL*64*512/2;
  // aliases (lifetimes don't overlap):
  __bf16* xp_bf = (__bf16*)xz;   // 3136*768 bf16 fits in xz
  float*  pemb  = u;             // 3136*256 fp32 fits in u

  // ---- weight prep (bf16 transposed copies; every call, graph-safe) ----
  transpose_bf16<<<dim3(1024/32, 256/32, NL), 256, 0, stream>>>(in_w,  wt_in, 256, 1024);
  transpose_bf16<<<dim3( 256/32, 512/32, NL), 256, 0, stream>>>(out_w, wt_out, 512, 256);
  transpose_bf16<<<dim3( 256/32, 768/32,  1), 256, 0, stream>>>(pe_w,  wt_pe, 768, 256);
  transpose_bf16_pad<<<dim3(2, 512/32, NL), 256, 0, stream>>>(xproj, wt_xp, 512, 48, 64);

  // ---- patch embed ----
  patch_ln1<<<NB*196, 256, 0, stream>>>(img, ln1g, ln1b, xp_bf);
  gemm_bf16<64,64><<<dim3(256/64, 3136/64), 256, 0, stream>>>(
      xp_bf, wt_pe, pe_b, pemb, 3136, 256, 768);
  ln2_cls_pos<<<NB*SEQL, 256, 0, stream>>>(pemb, ln2g, ln2b, pos, cls, x);

  for (int i = 0; i < NL; i++){
    add_ln<<<TB/4, 256, 0, stream>>>(x, resid, xn_bf, ln_w + i*DIMM, ln_b + i*DIMM, i == 0 ? 1 : 0);
    gemm_bf16<128,128><<<dim3(1024/128, (TB+127)/128), 256, 0, stream>>>(
        xn_bf, wt_in + (size_t)i*1024*256, nullptr, xz, TB, 1024, 256);
    conv_silu<<<TB*128/256, 256, 0, stream>>>(
        xz, conv_w + i*DI*4, conv_b + i*DI, u, u_bf);
    gemm_bf16<64,64><<<dim3(1, (TB+63)/64), 256, 0, stream>>>(
        u_bf, wt_xp + (size_t)i*64*512, nullptr, dbc, TB, 64, 512);
    scan_part<<<(NCH-1)*NB*64, 128, 0, stream>>>(
        u, dbc, A_log + i*DI*DS, dtw + i*16*DI, dtb + i*DI, hL_g, P_g);
    scan_carry<<<NCHAIN/256, 256, 0, stream>>>(hL_g, P_g, Hc_g);
    scan_final<<<NCH*NB*64, 128, 0, stream>>>(
        u, dbc, xz, A_log + i*DI*DS, Dp + i*DI, dtw + i*16*DI, dtb + i*DI, Hc_g, yg_bf);
    gemm_bf16<64,64><<<dim3(4, (TB+63)/64), 256, 0, stream>>>(
        yg_bf, wt_out + (size_t)i*256*512, nullptr, x, TB, DIMM, 512);
  }
  final_ln<<<NB, 256, 0, stream>>>(x, resid, nfw, nfb, xs_g);
  head_gemm<<<(1000+31)/32, 256, 0, stream>>>(xs_g, head_w, head_b, out);
}

// Round 11
// 682.782 us; speedup vs baseline: 1.3544x; 1.3544x over previous
//
#include <hip/hip_runtime.h>
#include <math.h>

#define NB   16      // batch
#define SEQL 197     // sequence length (196 patches + cls)
#define TB   (NB*SEQL)   // 3152 tokens
#define DIMM 256
#define DI   512
#define DS   16
#define NL   8

typedef __bf16 bf16x8 __attribute__((ext_vector_type(8)));
typedef __bf16 bf16x4 __attribute__((ext_vector_type(4)));
typedef float floatx4 __attribute__((ext_vector_type(4)));

// ---------------- block-wide 2-value reduction (256 threads = 4 waves) -----
__device__ __forceinline__ void block_reduce_2(float& s1, float& s2, float* red, int tid){
  #pragma unroll
  for (int off = 32; off > 0; off >>= 1){
    s1 += __shfl_down(s1, off, 64);
    s2 += __shfl_down(s2, off, 64);
  }
  __syncthreads();
  if ((tid & 63) == 0){ red[(tid>>6)*2] = s1; red[(tid>>6)*2+1] = s2; }
  __syncthreads();
  s1 = red[0] + red[2] + red[4] + red[6];
  s2 = red[1] + red[3] + red[5] + red[7];
}

// ---------------- weight cast+transpose: in[K][N] fp32 -> out[N][K] bf16 ---
__global__ __launch_bounds__(256) void transpose_bf16(
    const float* __restrict__ in, __bf16* __restrict__ out, int K, int N)
{
  __shared__ float t[32][33];
  const float* src = in  + (size_t)blockIdx.z*K*N;
  __bf16*      dst = out + (size_t)blockIdx.z*K*N;
  int n0 = blockIdx.x*32, k0 = blockIdx.y*32;
  int tx = threadIdx.x & 31, ty = threadIdx.x >> 5;   // 32 x 8
  #pragma unroll
  for (int j = 0; j < 4; j++)
    t[ty + j*8][tx] = src[(size_t)(k0 + ty + j*8)*N + n0 + tx];
  __syncthreads();
  #pragma unroll
  for (int j = 0; j < 4; j++)
    dst[(size_t)(n0 + ty + j*8)*K + k0 + tx] = (__bf16)t[tx][ty + j*8];
}

// in[K][Nin] fp32 -> out[Npad][K] bf16, rows >= Nin zeroed
__global__ __launch_bounds__(256) void transpose_bf16_pad(
    const float* __restrict__ in, __bf16* __restrict__ out, int K, int Nin, int Npad)
{
  __shared__ float t[32][33];
  const float* src = in  + (size_t)blockIdx.z*K*Nin;
  __bf16*      dst = out + (size_t)blockIdx.z*Npad*K;
  int n0 = blockIdx.x*32, k0 = blockIdx.y*32;
  int tx = threadIdx.x & 31, ty = threadIdx.x >> 5;
  #pragma unroll
  for (int j = 0; j < 4; j++){
    int n = n0 + tx;
    t[ty + j*8][tx] = (n < Nin) ? src[(size_t)(k0 + ty + j*8)*Nin + n] : 0.f;
  }
  __syncthreads();
  #pragma unroll
  for (int j = 0; j < 4; j++)
    dst[(size_t)(n0 + ty + j*8)*K + k0 + tx] = (__bf16)t[tx][ty + j*8];
}

// ---------------- bf16 MFMA GEMM: C fp32 = A[M][K] @ Wt[N][K]^T (+bias) ----
// Known-good BK=32 inner loop (R5/R7/R8). KS>1: split-K over blockIdx.x%KS,
// atomicAdd epilogue (C must be pre-zeroed; bias ignored).
template<int BM, int BN, int KS>
__global__ __launch_bounds__(256) void gemm_bf16(
    const __bf16* __restrict__ A, const __bf16* __restrict__ Wt,
    const float* __restrict__ bias, float* __restrict__ C, int M, int N, int K)
{
  constexpr int BK  = 32;
  constexpr int LDA = BK + 8;
  constexpr int TMW = BM/32;
  constexpr int TNW = BN/32;
  __shared__ __bf16 As[BM][LDA];
  __shared__ __bf16 Bs[BN][LDA];

  int tid  = threadIdx.x;
  int lane = tid & 63, w = tid >> 6;
  int wm = w >> 1, wn = w & 1;
  int l15 = lane & 15, quad = lane >> 4;
  int nt = blockIdx.x / KS, ks = blockIdx.x % KS;
  int bm = blockIdx.y * BM, bn = nt * BN;
  int kbeg = ks * (K / KS), kend = kbeg + (K / KS);

  floatx4 acc[TMW][TNW] = {};

  for (int k0 = kbeg; k0 < kend; k0 += BK){
    #pragma unroll
    for (int i = 0; i < BM/64; i++){
      int c = tid + i*256;
      int row = c >> 2, kc = c & 3;
      int m = bm + row;
      uint4 v = make_uint4(0,0,0,0);
      if (m < M) v = ((const uint4*)(A + (size_t)m*K + k0))[kc];
      *(uint4*)&As[row][kc*8] = v;
    }
    #pragma unroll
    for (int i = 0; i < BN/64; i++){
      int c = tid + i*256;
      int row = c >> 2, kc = c & 3;
      int n = bn + row;
      uint4 v = ((const uint4*)(Wt + (size_t)n*K + k0))[kc];
      *(uint4*)&Bs[row][kc*8] = v;
    }
    __syncthreads();
    bf16x8 af[TMW], bf[TNW];
    #pragma unroll
    for (int mi = 0; mi < TMW; mi++)
      af[mi] = *(const bf16x8*)&As[wm*(BM/2) + mi*16 + l15][quad*8];
    #pragma unroll
    for (int ni = 0; ni < TNW; ni++)
      bf[ni] = *(const bf16x8*)&Bs[wn*(BN/2) + ni*16 + l15][quad*8];
    #pragma unroll
    for (int mi = 0; mi < TMW; mi++)
      #pragma unroll
      for (int ni = 0; ni < TNW; ni++)
        acc[mi][ni] = __builtin_amdgcn_mfma_f32_16x16x32_bf16(af[mi], bf[ni], acc[mi][ni], 0, 0, 0);
    __syncthreads();
  }
  #pragma unroll
  for (int mi = 0; mi < TMW; mi++){
    #pragma unroll
    for (int ni = 0; ni < TNW; ni++){
      int col = bn + wn*(BN/2) + ni*16 + l15;
      float bv = (KS == 1 && bias) ? bias[col] : 0.f;
      #pragma unroll
      for (int r = 0; r < 4; r++){
        int row = bm + wm*(BM/2) + mi*16 + quad*4 + r;
        if (row < M){
          if (KS == 1) C[(size_t)row*N + col] = acc[mi][ni][r] + bv;
          else         atomicAdd(&C[(size_t)row*N + col], acc[mi][ni][r]);
        }
      }
    }
  }
}

// ---------------- patch LN1: gather + LayerNorm(768) -> bf16 ---------------
__global__ __launch_bounds__(256) void patch_ln1(
    const float* __restrict__ img, const float* __restrict__ g1, const float* __restrict__ b1,
    __bf16* __restrict__ xp_bf)
{
  __shared__ float red[8];
  int blk = blockIdx.x;            // b*196 + patch
  int b = blk / 196, p = blk % 196;
  int hh = p / 14, ww = p % 14;
  int tid = threadIdx.x;

  float v[3]; float s = 0.f, s2 = 0.f;
  #pragma unroll
  for (int i = 0; i < 3; i++){
    int e  = tid + i*256;
    int c  = e % 3;
    int p2 = (e/3) % 16;
    int p1 = e / 48;
    float val = img[((b*3 + c)*224 + hh*16 + p1)*224 + ww*16 + p2];
    v[i] = val; s += val; s2 += val*val;
  }
  block_reduce_2(s, s2, red, tid);
  float mu = s * (1.f/768.f);
  float var = s2 * (1.f/768.f) - mu*mu;
  float rr = rsqrtf(var + 1e-5f);
  #pragma unroll
  for (int i = 0; i < 3; i++){
    int e = tid + i*256;
    xp_bf[(size_t)blk*768 + e] = (__bf16)((v[i] - mu) * rr * g1[e] + b1[e]);
  }
}

// ---------------- patch LN2 + pos, and cls+pos (fused, grid NB*SEQL) -------
__global__ __launch_bounds__(256) void ln2_cls_pos(
    const float* __restrict__ pemb, const float* __restrict__ g2, const float* __restrict__ b2,
    const float* __restrict__ pos, const float* __restrict__ cls, float* __restrict__ x)
{
  __shared__ float red[8];
  int blk = blockIdx.x;            // b*197 + l
  int b = blk / SEQL, l = blk % SEQL;
  int tid = threadIdx.x;
  if (l == 0){
    x[(size_t)b*SEQL*256 + tid] = cls[tid] + pos[tid];
    return;
  }
  int p = l - 1;
  float v = pemb[(size_t)(b*196 + p)*256 + tid];
  float s = v, s2 = v*v;
  block_reduce_2(s, s2, red, tid);
  float mu = s * (1.f/256.f);
  float var = s2 * (1.f/256.f) - mu*mu;
  float rr = rsqrtf(var + 1e-5f);
  float o = (v - mu) * rr * g2[tid] + b2[tid] + pos[(1+p)*256 + tid];
  x[((size_t)(b*SEQL + 1 + p))*256 + tid] = o;
}

// ---------------- residual add + LayerNorm(256) -> bf16, wave-per-token ----
__global__ __launch_bounds__(256) void add_ln(
    const float* __restrict__ x, float* __restrict__ resid, __bf16* __restrict__ xn_bf,
    const float* __restrict__ g, const float* __restrict__ bta, int first)
{
  int w = threadIdx.x >> 6, l = threadIdx.x & 63;
  int t = blockIdx.x*4 + w;
  size_t base = (size_t)t*256 + l*4;
  float4 xv = *(const float4*)&x[base];
  if (!first){
    float4 rv = *(const float4*)&resid[base];
    xv.x += rv.x; xv.y += rv.y; xv.z += rv.z; xv.w += rv.w;
  }
  *(float4*)&resid[base] = xv;
  float s  = xv.x + xv.y + xv.z + xv.w;
  float s2 = xv.x*xv.x + xv.y*xv.y + xv.z*xv.z + xv.w*xv.w;
  #pragma unroll
  for (int off = 1; off < 64; off <<= 1){
    s  += __shfl_xor(s,  off, 64);
    s2 += __shfl_xor(s2, off, 64);
  }
  float mu = s * (1.f/256.f);
  float var = s2 * (1.f/256.f) - mu*mu;
  float rr = rsqrtf(var + 1e-5f);
  float4 gv = *(const float4*)&g[l*4];
  float4 bv = *(const float4*)&bta[l*4];
  bf16x4 o;
  o[0] = (__bf16)((xv.x - mu)*rr*gv.x + bv.x);
  o[1] = (__bf16)((xv.y - mu)*rr*gv.y + bv.y);
  o[2] = (__bf16)((xv.z - mu)*rr*gv.z + bv.z);
  o[3] = (__bf16)((xv.w - mu)*rr*gv.w + bv.w);
  *(bf16x4*)&xn_bf[base] = o;
}

// ---------------- causal depthwise conv (k=4) + SiLU, float4 ---------------
// Also zeroes dbc (16 float4/row) ahead of the split-K atomic xproj GEMM.
__global__ __launch_bounds__(256) void conv_silu(
    const float* __restrict__ xz, const float* __restrict__ cw, const float* __restrict__ cb,
    float* __restrict__ u, __bf16* __restrict__ u_bf, float* __restrict__ dbc)
{
  int gid = blockIdx.x*256 + threadIdx.x;   // t*128 + dq
  int dq = gid & 127;
  int t = gid >> 7;
  int d = dq*4;
  int l = t % SEQL;
  const float4 z4 = make_float4(0.f,0.f,0.f,0.f);
  if (dq < 16) *(float4*)&dbc[(size_t)t*64 + d] = z4;
  float4 x0 = *(const float4*)&xz[(size_t)t*1024 + d];
  float4 x1 = (l>=1) ? *(const float4*)&xz[(size_t)(t-1)*1024 + d] : z4;
  float4 x2 = (l>=2) ? *(const float4*)&xz[(size_t)(t-2)*1024 + d] : z4;
  float4 x3 = (l>=3) ? *(const float4*)&xz[(size_t)(t-3)*1024 + d] : z4;
  float4 w0 = *(const float4*)&cw[(d+0)*4];
  float4 w1 = *(const float4*)&cw[(d+1)*4];
  float4 w2 = *(const float4*)&cw[(d+2)*4];
  float4 w3 = *(const float4*)&cw[(d+3)*4];
  float4 r = *(const float4*)&cb[d];
  r.x += x3.x*w0.x + x2.x*w0.y + x1.x*w0.z + x0.x*w0.w;
  r.y += x3.y*w1.x + x2.y*w1.y + x1.y*w1.z + x0.y*w1.w;
  r.z += x3.z*w2.x + x2.z*w2.y + x1.z*w2.z + x0.z*w2.w;
  r.w += x3.w*w3.x + x2.w*w3.y + x1.w*w3.z + x0.w*w3.w;
  r.x *= 1.f/(1.f + __expf(-r.x));
  r.y *= 1.f/(1.f + __expf(-r.y));
  r.z *= 1.f/(1.f + __expf(-r.z));
  r.w *= 1.f/(1.f + __expf(-r.w));
  *(float4*)&u[(size_t)t*512 + d] = r;
  bf16x4 o; o[0]=(__bf16)r.x; o[1]=(__bf16)r.y; o[2]=(__bf16)r.z; o[3]=(__bf16)r.w;
  *(bf16x4*)&u_bf[(size_t)t*512 + d] = o;
}

// ---------------- selective scan + fused dtproj/softplus -------------------
// R8 known-good: 128 threads, 8 d-channels/block, 1024 blocks, s_yp LDS
// partials. Chunk-parallel (R9) and VGPR-yreg+shfl (R6) both regressed.
// dbc is [TB][64]: cols 0:16 dt_in, 16:32 B, 32:48 C.
#define SCT 32
#define NCH ((SEQL + SCT - 1)/SCT)   // 7
#define NDL 8                        // d-channels per block
__global__ __launch_bounds__(128) void scan_kernel(
    const float* __restrict__ u, const float* __restrict__ dbc,
    const float* __restrict__ xz, const float* __restrict__ A_log, const float* __restrict__ Dp,
    const float* __restrict__ dtw, const float* __restrict__ dtb,
    __bf16* __restrict__ yg_bf)
{
  __shared__ float s_D [16][36];        // dt_in  [k][tl]
  __shared__ float s_B [16][36];        // B      [n][tl]
  __shared__ float s_C [16][36];        // C      [n][tl]
  __shared__ float s_u [NDL][36];       // u      [dl][tl]
  __shared__ float s_z [NDL][36];       // z      [dl][tl]
  __shared__ float s_dt[NDL][36];       // softplus dt [dl][tl]
  __shared__ float s_yp[SCT][NDL][20];  // y partials [tl][dl][n]
  __shared__ float s_dp[NDL];

  int tid = threadIdx.x;                // 0..127 = dl*16 + n
  int n = tid & 15, dl = tid >> 4;      // dl 0..7
  int b = blockIdx.x >> 6, dg = blockIdx.x & 63;
  int d0 = dg * NDL;
  const size_t base = (size_t)b * SEQL;

  float A = -__expf(A_log[(d0+dl)*DS + n]);
  float h = 0.f;
  if (tid < NDL) s_dp[tid] = Dp[d0 + tid];
  int cch = tid & 7;                    // dt-proj output channel for this thread
  float wc[16];
  #pragma unroll
  for (int k = 0; k < 16; k++) wc[k] = dtw[k*512 + d0 + cch];
  float dtbv = dtb[d0 + cch];

  float r_u[2], r_z[2], r_db[12];
  auto load_regs = [&](int c){
    #pragma unroll
    for (int i = 0; i < 2; i++){
      int v = tid + i*128;
      int tg = c*SCT + (v>>3); if (tg > SEQL-1) tg = SEQL-1;
      size_t t = base + tg;
      r_u[i] = u [t*512 + d0 + (v&7)];
      r_z[i] = xz[t*1024 + 512 + d0 + (v&7)];
    }
    #pragma unroll
    for (int s = 0; s < 3; s++)
      #pragma unroll
      for (int i = 0; i < 4; i++){
        int v = tid + i*128;
        int tg = c*SCT + (v>>4); if (tg > SEQL-1) tg = SEQL-1;
        r_db[s*4+i] = dbc[(base + tg)*64 + s*16 + (v&15)];
      }
  };
  auto write_DBC = [&](){
    #pragma unroll
    for (int i = 0; i < 4; i++){
      int v = tid + i*128;
      s_D[v&15][v>>4] = r_db[0+i];
      s_B[v&15][v>>4] = r_db[4+i];
      s_C[v&15][v>>4] = r_db[8+i];
    }
  };
  auto write_UZ = [&](){
    #pragma unroll
    for (int i = 0; i < 2; i++){
      int v = tid + i*128;
      s_u[v&7][v>>3] = r_u[i];
      s_z[v&7][v>>3] = r_z[i];
    }
  };
  auto compute_dt = [&](){
    #pragma unroll
    for (int i = 0; i < 2; i++){
      int tl = (tid >> 3) + i*16;
      float acc = dtbv;
      #pragma unroll
      for (int k = 0; k < 16; k++) acc += s_D[k][tl] * wc[k];
      s_dt[cch][tl] = (acc > 20.f) ? acc : log1pf(__expf(acc));
    }
  };

  // prologue: stage chunk 0
  load_regs(0);
  write_DBC();
  write_UZ();
  __syncthreads();
  compute_dt();
  __syncthreads();

  for (int c = 0; c < NCH; c++){
    if (c + 1 < NCH) load_regs(c+1);        // global loads in flight over compute

    // ---- hot loop: 32 steps, unrolled, no cross-lane deps ----
    float4 dt4, u4, B4, C4;
    #pragma unroll
    for (int tl = 0; tl < SCT; tl++){
      if ((tl & 3) == 0){
        dt4 = *(const float4*)&s_dt[dl][tl];
        u4  = *(const float4*)&s_u [dl][tl];
        B4  = *(const float4*)&s_B [n][tl];
        C4  = *(const float4*)&s_C [n][tl];
      }
      float dtv = ((float*)&dt4)[tl&3];
      float uv  = ((float*)&u4 )[tl&3];
      float Bv  = ((float*)&B4 )[tl&3];
      float Cv  = ((float*)&C4 )[tl&3];
      h = __expf(dtv * A) * h + (dtv * uv) * Bv;
      s_yp[tl][dl][n] = h * Cv;
    }
    __syncthreads();                         // (1) y-partials visible

    if (c + 1 < NCH) write_DBC();            // stage next D/B/C

    // ---- reduction + gate + store ----
    #pragma unroll
    for (int j = 0; j < 2; j++){
      int p = tid + j*128;
      int tl = p >> 3, dr = p & 7;
      float4 a0 = *(const float4*)&s_yp[tl][dr][0];
      float4 a1 = *(const float4*)&s_yp[tl][dr][4];
      float4 a2 = *(const float4*)&s_yp[tl][dr][8];
      float4 a3 = *(const float4*)&s_yp[tl][dr][12];
      float yv = ((a0.x+a0.y)+(a0.z+a0.w)) + ((a1.x+a1.y)+(a1.z+a1.w))
               + ((a2.x+a2.y)+(a2.z+a2.w)) + ((a3.x+a3.y)+(a3.z+a3.w));
      int tg = c*SCT + tl;
      if (tg < SEQL){
        float uv = s_u[dr][tl];
        float zv = s_z[dr][tl];
        float sg = 1.f / (1.f + __expf(-zv));
        yg_bf[(base + tg)*512 + d0 + dr] = (__bf16)((yv + uv*s_dp[dr]) * zv * sg);
      }
    }
    __syncthreads();                         // (2) u/z reads done; s_D complete

    if (c + 1 < NCH){
      write_UZ();
      compute_dt();
      __syncthreads();                       // (3) s_dt/s_u/s_z ready
    }
  }
}

// ---------------- final LN (token 0) ---------------------------------------
__global__ __launch_bounds__(256) void final_ln(
    const float* __restrict__ x, const float* __restrict__ resid,
    const float* __restrict__ g, const float* __restrict__ bta, float* __restrict__ xs_g)
{
  __shared__ float red[8];
  int b = blockIdx.x, tid = threadIdx.x;
  size_t idx = (size_t)b*SEQL*256 + tid;
  float r = x[idx] + resid[idx];
  float s = r, s2 = r*r;
  block_reduce_2(s, s2, red, tid);
  float mu = s * (1.f/256.f);
  float var = s2 * (1.f/256.f) - mu*mu;
  float rr = rsqrtf(var + 1e-5f);
  xs_g[b*256 + tid] = (r - mu) * rr * g[tid] + bta[tid];
}

// ---------------- head: out[16][1000] = xs[16][256] @ head_w + head_b ------
__global__ __launch_bounds__(256) void head_gemm(
    const float* __restrict__ xs_g, const float* __restrict__ head_w,
    const float* __restrict__ head_b, float* __restrict__ out)
{
  __shared__ float xs[16][256];
  int tid = threadIdx.x;
  #pragma unroll
  for (int i = 0; i < 16; i++) ((float*)xs)[tid + i*256] = xs_g[tid + i*256];
  __syncthreads();
  int nl = tid & 31, bq = tid >> 5;
  int nn = blockIdx.x*32 + nl;
  if (nn >= 1000) return;
  float acc0 = 0.f, acc1 = 0.f;
  #pragma unroll 8
  for (int k = 0; k < 256; k++){
    float w = head_w[k*1000 + nn];
    acc0 += xs[bq][k]   * w;
    acc1 += xs[bq+8][k] * w;
  }
  float hb = head_b[nn];
  out[(size_t)bq*1000 + nn]     = acc0 + hb;
  out[(size_t)(bq+8)*1000 + nn] = acc1 + hb;
}

// ---------------------------------------------------------------------------
extern "C" void kernel_launch(void* const* d_in, const int* in_sizes, int n_in,
                              void* d_out, int out_size, void* d_ws, size_t ws_size,
                              hipStream_t stream) {
  const float* img   = (const float*)d_in[0];
  const float* ln1g  = (const float*)d_in[1];
  const float* ln1b  = (const float*)d_in[2];
  const float* pe_w  = (const float*)d_in[3];
  const float* pe_b  = (const float*)d_in[4];
  const float* ln2g  = (const float*)d_in[5];
  const float* ln2b  = (const float*)d_in[6];
  const float* pos   = (const float*)d_in[7];
  const float* cls   = (const float*)d_in[8];
  const float* ln_w  = (const float*)d_in[9];
  const float* ln_b  = (const float*)d_in[10];
  const float* in_w  = (const float*)d_in[11];
  const float* conv_w= (const float*)d_in[12];
  const float* conv_b= (const float*)d_in[13];
  const float* xproj = (const float*)d_in[14];
  const float* dtw   = (const float*)d_in[15];
  const float* dtb   = (const float*)d_in[16];
  const float* A_log = (const float*)d_in[17];
  const float* Dp    = (const float*)d_in[18];
  const float* out_w = (const float*)d_in[19];
  const float* nfw   = (const float*)d_in[20];
  const float* nfb   = (const float*)d_in[21];
  const float* head_w= (const float*)d_in[22];
  const float* head_b= (const float*)d_in[23];
  float* out = (float*)d_out;

  float* ws = (float*)d_ws;
  float* x     = ws;  ws += (size_t)TB*DIMM;
  float* resid = ws;  ws += (size_t)TB*DIMM;
  float* xz    = ws;  ws += (size_t)TB*2*DI;
  float* u     = ws;  ws += (size_t)TB*DI;
  float* dbc   = ws;  ws += (size_t)TB*64;      // padded N=64 layout
  float* xs_g  = ws;  ws += (size_t)NB*DIMM;
  __bf16* xn_bf = (__bf16*)ws;  ws += (size_t)TB*DIMM/2;
  __bf16* u_bf  = (__bf16*)ws;  ws += (size_t)TB*DI/2;
  __bf16* yg_bf = (__bf16*)ws;  ws += (size_t)TB*DI/2;
  __bf16* wt_in = (__bf16*)ws;  ws += (size_t)NL*1024*256/2;
  __bf16* wt_out= (__bf16*)ws;  ws += (size_t)NL*256*512/2;
  __bf16* wt_pe = (__bf16*)ws;  ws += (size_t)256*768/2;
  __bf16* wt_xp = (__bf16*)ws;  ws += (size_t)NL*64*512/2;
  // aliases (lifetimes don't overlap):
  __bf16* xp_bf = (__bf16*)xz;   // 3136*768 bf16 fits in xz
  float*  pemb  = u;             // 3136*256 fp32 fits in u

  // ---- weight prep (bf16 transposed copies; every call, graph-safe) ----
  transpose_bf16<<<dim3(1024/32, 256/32, NL), 256, 0, stream>>>(in_w,  wt_in, 256, 1024);
  transpose_bf16<<<dim3( 256/32, 512/32, NL), 256, 0, stream>>>(out_w, wt_out, 512, 256);
  transpose_bf16<<<dim3( 256/32, 768/32,  1), 256, 0, stream>>>(pe_w,  wt_pe, 768, 256);
  transpose_bf16_pad<<<dim3(2, 512/32, NL), 256, 0, stream>>>(xproj, wt_xp, 512, 48, 64);

  // ---- patch embed ----
  patch_ln1<<<NB*196, 256, 0, stream>>>(img, ln1g, ln1b, xp_bf);
  gemm_bf16<64,64,1><<<dim3(256/64, 3136/64), 256, 0, stream>>>(
      xp_bf, wt_pe, pe_b, pemb, 3136, 256, 768);
  ln2_cls_pos<<<NB*SEQL, 256, 0, stream>>>(pemb, ln2g, ln2b, pos, cls, x);

  for (int i = 0; i < NL; i++){
    add_ln<<<TB/4, 256, 0, stream>>>(x, resid, xn_bf, ln_w + i*DIMM, ln_b + i*DIMM, i == 0 ? 1 : 0);
    gemm_bf16<64,128,1><<<dim3(1024/128, (TB+63)/64), 256, 0, stream>>>(
        xn_bf, wt_in + (size_t)i*1024*256, nullptr, xz, TB, 1024, 256);
    conv_silu<<<TB*128/256, 256, 0, stream>>>(
        xz, conv_w + i*DI*4, conv_b + i*DI, u, u_bf, dbc);
    gemm_bf16<64,64,4><<<dim3(4, (TB+63)/64), 256, 0, stream>>>(
        u_bf, wt_xp + (size_t)i*64*512, nullptr, dbc, TB, 64, 512);
    scan_kernel<<<NB*64, 128, 0, stream>>>(
        u, dbc, xz, A_log + i*DI*DS, Dp + i*DI, dtw + i*16*DI, dtb + i*DI, yg_bf);
    gemm_bf16<64,64,1><<<dim3(4, (TB+63)/64), 256, 0, stream>>>(
        yg_bf, wt_out + (size_t)i*256*512, nullptr, x, TB, DIMM, 512);
  }
  final_ln<<<NB, 256, 0, stream>>>(x, resid, nfw, nfb, xs_g);
  head_gemm<<<(1000+31)/32, 256, 0, stream>>>(xs_g, head_w, head_b, out);
}